// Round 1
// baseline (487.811 us; speedup 1.0000x reference)
//
#include <hip/hip_runtime.h>

#define L2E 1.44269504088896340736f
#define INV_SCALE 0.08838834764831845f  // 1/sqrt(128)

typedef _Float16 half8 __attribute__((ext_vector_type(8)));
typedef float f32x4 __attribute__((ext_vector_type(4)));

__device__ __forceinline__ float exp2_fast(float x) {
#if __has_builtin(__builtin_amdgcn_exp2f)
  return __builtin_amdgcn_exp2f(x);
#else
  return exp2f(x);
#endif
}

__device__ __forceinline__ f32x4 mfma16(half8 a, half8 b, f32x4 c) {
  return __builtin_amdgcn_mfma_f32_16x16x32_f16(a, b, c, 0, 0, 0);
}

__device__ __forceinline__ void gload16(const void* g, void* l) {
  __builtin_amdgcn_global_load_lds(
      (const __attribute__((address_space(1))) void*)g,
      (__attribute__((address_space(3))) void*)l, 16, 0, 0);
}

__device__ __forceinline__ float swish_f(float v) {
  return v / (1.f + exp2_fast(-L2E * v));
}

// ---------------------------------------------------------------------------
// Kernel 1: Q/K/V projections (f16 MFMA), outputs in MFMA-fragment order.
// Q layout:  [rowtile(16 rows) 0..1023][kc 0..3][lane 0..63] * 8 f16
//            lane holds Q[rt*16 + (lane&15)][kc*32 + (lane>>4)*8 + j]
// K layout:  [tile(32 rows) 0..511][ct 0..1][kc 0..3][lane] * 8 f16
//            lane holds K[tile*32 + ct*16 + (lane&15)][kc*32 + (lane>>4)*8 + j]
// V layout:  [tile(32 rows) 0..511][dt 0..7][lane] * 8 f16
//            lane holds V[tile*32 + (lane>>4)*8 + j][dt*16 + (lane&15)]
// ---------------------------------------------------------------------------
__device__ __forceinline__ void stage_wt(const float* __restrict__ W,
                                         _Float16* wt, int tid) {
  const int nn = tid >> 1, hf = tid & 1;
#pragma unroll
  for (int i = 0; i < 32; ++i) {
    const int k = hf * 64 + 2 * i;
    wt[nn * 136 + k]     = (_Float16)W[k * 128 + nn];
    wt[nn * 136 + k + 1] = (_Float16)W[(k + 1) * 128 + nn];
  }
}

__global__ __launch_bounds__(256) void qkv_kernel(
    const float* __restrict__ x,
    const float* __restrict__ Wq, const float* __restrict__ Wk,
    const float* __restrict__ Wv,
    _Float16* __restrict__ Qg, _Float16* __restrict__ Kg,
    _Float16* __restrict__ Vg) {
  __shared__ __align__(16) _Float16 wt[128 * 136];
  __shared__ __align__(16) _Float16 sc[64 * 136];
  const int tid = threadIdx.x;
  const int w = tid >> 6, lane = tid & 63;
  const int n16 = lane & 15, quad = lane >> 4;
  const int blk = blockIdx.x;  // 64 rows per block, 256 blocks

  // x A-fragments, direct from global (L1/L2 cached), converted to f16
  half8 xf[4];
  {
    const float* xr = x + (size_t)(blk * 64 + w * 16 + n16) * 128 + quad * 8;
#pragma unroll
    for (int kc = 0; kc < 4; ++kc) {
      float4 a = *(const float4*)(xr + kc * 32);
      float4 b = *(const float4*)(xr + kc * 32 + 4);
      half8 h;
      h[0] = (_Float16)a.x; h[1] = (_Float16)a.y;
      h[2] = (_Float16)a.z; h[3] = (_Float16)a.w;
      h[4] = (_Float16)b.x; h[5] = (_Float16)b.y;
      h[6] = (_Float16)b.z; h[7] = (_Float16)b.w;
      xf[kc] = h;
    }
  }
  const float* Ws[3] = {Wq, Wk, Wv};

  for (int mat = 0; mat < 3; ++mat) {
    stage_wt(Ws[mat], wt, tid);
    __syncthreads();
    f32x4 acc[8];
#pragma unroll
    for (int ct = 0; ct < 8; ++ct) acc[ct] = f32x4{0.f, 0.f, 0.f, 0.f};
#pragma unroll
    for (int ct = 0; ct < 8; ++ct) {
#pragma unroll
      for (int kc = 0; kc < 4; ++kc) {
        half8 wf = *(const half8*)&wt[(ct * 16 + n16) * 136 + kc * 32 + quad * 8];
        acc[ct] = mfma16(xf[kc], wf, acc[ct]);
      }
    }
    // C-layout -> scratch (row-major, padded 136)
#pragma unroll
    for (int ct = 0; ct < 8; ++ct)
#pragma unroll
      for (int r = 0; r < 4; ++r)
        sc[(w * 16 + quad * 4 + r) * 136 + ct * 16 + n16] = (_Float16)acc[ct][r];
    __syncthreads();

    if (mat == 0) {  // Q
#pragma unroll
      for (int i = 0; i < 4; ++i) {
        const int c = tid + 256 * i;
        const int ln = c & 63, qc = (c >> 6) & 3, rt = c >> 8;
        half8 v = *(const half8*)&sc[(rt * 16 + (ln & 15)) * 136 + qc * 32 + (ln >> 4) * 8];
        *(half8*)(Qg + ((((size_t)(blk * 4 + rt)) * 4 + qc) * 64 + ln) * 8) = v;
      }
    } else if (mat == 1) {  // K
#pragma unroll
      for (int i = 0; i < 4; ++i) {
        const int c = tid + 256 * i;
        const int ln = c & 63, kc = (c >> 6) & 3, ct = (c >> 8) & 1, tl = (c >> 9) & 1;
        half8 v = *(const half8*)&sc[(tl * 32 + ct * 16 + (ln & 15)) * 136 + kc * 32 + (ln >> 4) * 8];
        *(half8*)(Kg + (((((size_t)(blk * 2 + tl)) * 2 + ct) * 4 + kc) * 64 + ln) * 8) = v;
      }
    } else {  // V (transposed fragments)
#pragma unroll
      for (int i = 0; i < 4; ++i) {
        const int c = tid + 256 * i;
        const int ln = c & 63, dt = (c >> 6) & 7, tl = (c >> 9) & 1;
        const int q2 = ln >> 4, nn = ln & 15;
        half8 v;
#pragma unroll
        for (int j = 0; j < 8; ++j)
          v[j] = sc[(tl * 32 + q2 * 8 + j) * 136 + dt * 16 + nn];
        *(half8*)(Vg + ((((size_t)(blk * 2 + tl)) * 8 + dt) * 64 + ln) * 8) = v;
      }
    }
    __syncthreads();
  }
}

// ---------------------------------------------------------------------------
// Kernel 2: flash attention with additive connectivity bias.
// 256 blocks (b = bid&3 for XCD/L2 locality), 4 waves, 16 q-rows per wave,
// 128 kv-tiles of 32, double-buffered global_load_lds staging.
// ---------------------------------------------------------------------------
__global__ __launch_bounds__(256) void flash_kernel(
    const float* __restrict__ conn,
    const _Float16* __restrict__ Qg, const _Float16* __restrict__ Kg,
    const _Float16* __restrict__ Vg, _Float16* __restrict__ Hg) {
  __shared__ __align__(16) _Float16 kb0[4096], vb0[4096], kb1[4096], vb1[4096];
  __shared__ __align__(16) _Float16 pb[4][640];   // per-wave P, rows padded to 40
  __shared__ __align__(16) _Float16 hb[4][2176];  // per-wave epilogue, rows 136

  const int tid = threadIdx.x, w = tid >> 6, lane = tid & 63;
  const int n16 = lane & 15, quad = lane >> 4;
  const int bid = blockIdx.x;
  const int b = bid & 3, g = bid >> 2;        // batch, q-group (64 rows)
  const int rt_g = (b * 64 + g) * 4 + w;      // global rowtile of this wave

  half8 qf[4];
#pragma unroll
  for (int kc = 0; kc < 4; ++kc)
    qf[kc] = *(const half8*)(Qg + (((size_t)rt_g * 4 + kc) * 64 + lane) * 8);

  f32x4 o[8];
#pragma unroll
  for (int dt = 0; dt < 8; ++dt) o[dt] = f32x4{0.f, 0.f, 0.f, 0.f};
  float m_i[4] = {-__builtin_inff(), -__builtin_inff(), -__builtin_inff(), -__builtin_inff()};
  float l_i[4] = {0.f, 0.f, 0.f, 0.f};

  const _Float16* ktile = Kg + (size_t)b * 128 * 4096;
  const _Float16* vtile = Vg + (size_t)b * 128 * 4096;
  const float* cp = conn + (size_t)b * 4096 * 4096 +
                    (size_t)(g * 64 + w * 16 + quad * 4) * 4096 + n16;
  _Float16* pw = pb[w];
  const int wbase = (tid & ~63) * 8;  // wave-uniform LDS chunk base

  auto stage = [&](int t2, _Float16* kd, _Float16* vd) {
#pragma unroll
    for (int i = 0; i < 2; ++i) {
      gload16(ktile + (size_t)t2 * 4096 + tid * 8 + i * 2048, kd + wbase + i * 2048);
      gload16(vtile + (size_t)t2 * 4096 + tid * 8 + i * 2048, vd + wbase + i * 2048);
    }
  };
  auto ldconn = [&](int t2, float* cr) {
#pragma unroll
    for (int ct = 0; ct < 2; ++ct)
#pragma unroll
      for (int r = 0; r < 4; ++r)
        cr[ct * 4 + r] = cp[(size_t)r * 4096 + t2 * 32 + ct * 16];
  };

  float c_cur[8], c_nxt[8];
  stage(0, kb0, vb0);
  ldconn(0, c_cur);
  __syncthreads();

  auto body = [&](int t, const _Float16* kcur, const _Float16* vcur,
                  _Float16* knxt, _Float16* vnxt, float* cc, float* cn) {
    if (t + 1 < 128) {
      stage(t + 1, knxt, vnxt);
      ldconn(t + 1, cn);
    }
    f32x4 s[2];
    s[0] = f32x4{0.f, 0.f, 0.f, 0.f};
    s[1] = f32x4{0.f, 0.f, 0.f, 0.f};
#pragma unroll
    for (int ct = 0; ct < 2; ++ct)
#pragma unroll
      for (int kc = 0; kc < 4; ++kc) {
        half8 kf = *(const half8*)(kcur + ((ct * 4 + kc) * 64 + lane) * 8);
        s[ct] = mfma16(qf[kc], kf, s[ct]);
      }
    const float c1 = L2E * INV_SCALE;
    float pr[8];
#pragma unroll
    for (int ct = 0; ct < 2; ++ct)
#pragma unroll
      for (int r = 0; r < 4; ++r)
        pr[ct * 4 + r] = s[ct][r] * c1 + cc[ct * 4 + r] * L2E;
    float mt[4];
#pragma unroll
    for (int r = 0; r < 4; ++r) mt[r] = fmaxf(pr[r], pr[4 + r]);
#pragma unroll
    for (int mask = 1; mask <= 8; mask <<= 1)
#pragma unroll
      for (int r = 0; r < 4; ++r)
        mt[r] = fmaxf(mt[r], __shfl_xor(mt[r], mask, 64));
    float al[4];
#pragma unroll
    for (int r = 0; r < 4; ++r) {
      float mn = fmaxf(m_i[r], mt[r]);
      al[r] = exp2_fast(m_i[r] - mn);
      m_i[r] = mn;
    }
#pragma unroll
    for (int ct = 0; ct < 2; ++ct)
#pragma unroll
      for (int r = 0; r < 4; ++r)
        pr[ct * 4 + r] = exp2_fast(pr[ct * 4 + r] - m_i[r]);
    float rs[4];
#pragma unroll
    for (int r = 0; r < 4; ++r) rs[r] = pr[r] + pr[4 + r];
#pragma unroll
    for (int mask = 1; mask <= 8; mask <<= 1)
#pragma unroll
      for (int r = 0; r < 4; ++r) rs[r] += __shfl_xor(rs[r], mask, 64);
#pragma unroll
    for (int r = 0; r < 4; ++r) l_i[r] = l_i[r] * al[r] + rs[r];
#pragma unroll
    for (int dt = 0; dt < 8; ++dt)
#pragma unroll
      for (int r = 0; r < 4; ++r) o[dt][r] *= al[r];
    // P: C-layout -> A-layout via per-wave LDS (rows padded to 40 f16)
#pragma unroll
    for (int ct = 0; ct < 2; ++ct)
#pragma unroll
      for (int r = 0; r < 4; ++r)
        pw[(quad * 4 + r) * 40 + ct * 16 + n16] = (_Float16)pr[ct * 4 + r];
    half8 pf = *(const half8*)(pw + n16 * 40 + quad * 8);
#pragma unroll
    for (int dt = 0; dt < 8; ++dt) {
      half8 vf = *(const half8*)(vcur + (dt * 64 + lane) * 8);
      o[dt] = mfma16(pf, vf, o[dt]);
    }
    __syncthreads();
  };

#pragma unroll 1
  for (int t = 0; t < 128; t += 2) {
    body(t, kb0, vb0, kb1, vb1, c_cur, c_nxt);
    body(t + 1, kb1, vb1, kb0, vb0, c_nxt, c_cur);
  }

  // epilogue: O /= l, store H in A-fragment order
  float il[4];
#pragma unroll
  for (int r = 0; r < 4; ++r) il[r] = 1.0f / l_i[r];
  _Float16* hw = hb[w];
#pragma unroll
  for (int dt = 0; dt < 8; ++dt)
#pragma unroll
    for (int r = 0; r < 4; ++r)
      hw[(quad * 4 + r) * 136 + dt * 16 + n16] = (_Float16)(o[dt][r] * il[r]);
#pragma unroll
  for (int kc = 0; kc < 4; ++kc) {
    half8 hf = *(const half8*)(hw + n16 * 136 + kc * 32 + quad * 8);
    *(half8*)(Hg + (((size_t)rt_g * 4 + kc) * 64 + lane) * 8) = hf;
  }
}

// ---------------------------------------------------------------------------
// Kernel 3: swish -> @W1 + b1 -> swish -> @W2 + b2 -> LayerNorm -> out (fp32)
// ---------------------------------------------------------------------------
__global__ __launch_bounds__(256) void mlp_kernel(
    const _Float16* __restrict__ Hg,
    const float* __restrict__ W1, const float* __restrict__ b1,
    const float* __restrict__ W2, const float* __restrict__ b2,
    const float* __restrict__ gamma, const float* __restrict__ beta,
    float* __restrict__ out) {
  __shared__ __align__(16) _Float16 wt[128 * 136];
  __shared__ __align__(16) _Float16 hb[4][2176];
  const int tid = threadIdx.x, w = tid >> 6, lane = tid & 63;
  const int n16 = lane & 15, quad = lane >> 4;
  const int rt_g = blockIdx.x * 4 + w;

  half8 hf[4];
#pragma unroll
  for (int kc = 0; kc < 4; ++kc)
    hf[kc] = *(const half8*)(Hg + (((size_t)rt_g * 4 + kc) * 64 + lane) * 8);
#pragma unroll
  for (int kc = 0; kc < 4; ++kc)
#pragma unroll
    for (int j = 0; j < 8; ++j)
      hf[kc][j] = (_Float16)swish_f((float)hf[kc][j]);

  float b1v[8], b2v[8], gv[8], bv[8];
#pragma unroll
  for (int ct = 0; ct < 8; ++ct) {
    b1v[ct] = b1[ct * 16 + n16];
    b2v[ct] = b2[ct * 16 + n16];
    gv[ct] = gamma[ct * 16 + n16];
    bv[ct] = beta[ct * 16 + n16];
  }

  stage_wt(W1, wt, tid);
  __syncthreads();

  f32x4 acc[8];
#pragma unroll
  for (int ct = 0; ct < 8; ++ct) acc[ct] = f32x4{0.f, 0.f, 0.f, 0.f};
#pragma unroll
  for (int ct = 0; ct < 8; ++ct)
#pragma unroll
    for (int kc = 0; kc < 4; ++kc) {
      half8 wf = *(const half8*)&wt[(ct * 16 + n16) * 136 + kc * 32 + quad * 8];
      acc[ct] = mfma16(hf[kc], wf, acc[ct]);
    }
  _Float16* hw = hb[w];
#pragma unroll
  for (int ct = 0; ct < 8; ++ct)
#pragma unroll
    for (int r = 0; r < 4; ++r)
      hw[(quad * 4 + r) * 136 + ct * 16 + n16] =
          (_Float16)swish_f(acc[ct][r] + b1v[ct]);
  half8 h1f[4];
#pragma unroll
  for (int kc = 0; kc < 4; ++kc)
    h1f[kc] = *(const half8*)(hw + n16 * 136 + kc * 32 + quad * 8);
  __syncthreads();
  stage_wt(W2, wt, tid);
  __syncthreads();
#pragma unroll
  for (int ct = 0; ct < 8; ++ct) acc[ct] = f32x4{0.f, 0.f, 0.f, 0.f};
#pragma unroll
  for (int ct = 0; ct < 8; ++ct)
#pragma unroll
    for (int kc = 0; kc < 4; ++kc) {
      half8 wf = *(const half8*)&wt[(ct * 16 + n16) * 136 + kc * 32 + quad * 8];
      acc[ct] = mfma16(h1f[kc], wf, acc[ct]);
    }
  float hx[8][4];
  float sm[4] = {0, 0, 0, 0}, ss[4] = {0, 0, 0, 0};
#pragma unroll
  for (int ct = 0; ct < 8; ++ct)
#pragma unroll
    for (int r = 0; r < 4; ++r) {
      float v = acc[ct][r] + b2v[ct];
      hx[ct][r] = v;
      sm[r] += v;
      ss[r] += v * v;
    }
#pragma unroll
  for (int mask = 1; mask <= 8; mask <<= 1)
#pragma unroll
    for (int r = 0; r < 4; ++r) {
      sm[r] += __shfl_xor(sm[r], mask, 64);
      ss[r] += __shfl_xor(ss[r], mask, 64);
    }
#pragma unroll
  for (int r = 0; r < 4; ++r) {
    const float mu = sm[r] * (1.f / 128.f);
    const float var = ss[r] * (1.f / 128.f) - mu * mu;
    const float rstd = rsqrtf(var + 1e-5f);
    const size_t row = (size_t)rt_g * 16 + quad * 4 + r;
#pragma unroll
    for (int ct = 0; ct < 8; ++ct)
      out[row * 128 + ct * 16 + n16] = (hx[ct][r] - mu) * rstd * gv[ct] + bv[ct];
  }
}

extern "C" void kernel_launch(void* const* d_in, const int* in_sizes, int n_in,
                              void* d_out, int out_size, void* d_ws,
                              size_t ws_size, hipStream_t stream) {
  const float* x     = (const float*)d_in[0];
  const float* conn  = (const float*)d_in[1];
  const float* Wq    = (const float*)d_in[2];
  const float* Wk    = (const float*)d_in[3];
  const float* Wv    = (const float*)d_in[4];
  const float* W1    = (const float*)d_in[5];
  const float* b1    = (const float*)d_in[6];
  const float* W2    = (const float*)d_in[7];
  const float* b2    = (const float*)d_in[8];
  const float* gamma = (const float*)d_in[9];
  const float* beta  = (const float*)d_in[10];
  float* out = (float*)d_out;

  const size_t N = (size_t)16384 * 128;  // elements per tensor
  _Float16* Qg = (_Float16*)d_ws;
  _Float16* Kg = Qg + N;
  _Float16* Vg = Kg + N;
  _Float16* Hg = Vg + N;

  qkv_kernel<<<256, 256, 0, stream>>>(x, Wq, Wk, Wv, Qg, Kg, Vg);
  flash_kernel<<<256, 256, 0, stream>>>(conn, Qg, Kg, Vg, Hg);
  mlp_kernel<<<256, 256, 0, stream>>>(Hg, W1, b1, W2, b2, gamma, beta, out);
}

// Round 2
// 470.056 us; speedup vs baseline: 1.0378x; 1.0378x over previous
//
#include <hip/hip_runtime.h>

#define L2E 1.44269504088896340736f
#define INV_SCALE 0.08838834764831845f  // 1/sqrt(128)

typedef _Float16 half8 __attribute__((ext_vector_type(8)));
typedef float f32x4 __attribute__((ext_vector_type(4)));

__device__ __forceinline__ float exp2_fast(float x) {
#if __has_builtin(__builtin_amdgcn_exp2f)
  return __builtin_amdgcn_exp2f(x);
#else
  return exp2f(x);
#endif
}

__device__ __forceinline__ f32x4 mfma16(half8 a, half8 b, f32x4 c) {
  return __builtin_amdgcn_mfma_f32_16x16x32_f16(a, b, c, 0, 0, 0);
}

__device__ __forceinline__ void gload16(const void* g, void* l) {
  __builtin_amdgcn_global_load_lds(
      (const __attribute__((address_space(1))) void*)g,
      (__attribute__((address_space(3))) void*)l, 16, 0, 0);
}

__device__ __forceinline__ float swish_f(float v) {
  return v / (1.f + exp2_fast(-L2E * v));
}

// DPP cross-lane within 16-lane rows (single-cycle VALU, no LDS latency)
template <int CTRL>
__device__ __forceinline__ float dppmov(float x) {
  int xi = __builtin_bit_cast(int, x);
  int r = __builtin_amdgcn_update_dpp(xi, xi, CTRL, 0xf, 0xf, false);
  return __builtin_bit_cast(float, r);
}
__device__ __forceinline__ float red16_max(float x) {
  x = fmaxf(x, dppmov<0xB1>(x));   // quad_perm [1,0,3,2]
  x = fmaxf(x, dppmov<0x4E>(x));   // quad_perm [2,3,0,1]
  x = fmaxf(x, dppmov<0x141>(x));  // row_half_mirror
  x = fmaxf(x, dppmov<0x140>(x));  // row_mirror
  return x;
}
__device__ __forceinline__ float red16_sum(float x) {
  x += dppmov<0xB1>(x);
  x += dppmov<0x4E>(x);
  x += dppmov<0x141>(x);
  x += dppmov<0x140>(x);
  return x;
}

// ---------------------------------------------------------------------------
// prep: build f16 B-fragment images of the 5 weight matrices.
// Image layout per mat m, frag f = ct*4+kc:  Wf[((m*32+f)*64+lane)*8 + j]
//   = W[k][n], n = ct*16 + (lane&15), k = kc*32 + (lane>>4)*8 + j
// ---------------------------------------------------------------------------
__global__ __launch_bounds__(256) void prep_kernel(
    const float* __restrict__ Wq, const float* __restrict__ Wk,
    const float* __restrict__ Wv, const float* __restrict__ W1,
    const float* __restrict__ W2, _Float16* __restrict__ Wf) {
  const int g = blockIdx.x * 256 + threadIdx.x;  // [0, 10240)
  const int mat = g >> 11, rem = g & 2047;
  const int f = rem >> 6, lane = rem & 63;
  const int n = (f >> 2) * 16 + (lane & 15);
  const int k0 = (f & 3) * 32 + (lane >> 4) * 8;
  const float* W = (mat == 0) ? Wq : (mat == 1) ? Wk : (mat == 2) ? Wv
                   : (mat == 3) ? W1 : W2;
  half8 h;
#pragma unroll
  for (int j = 0; j < 8; ++j) h[j] = (_Float16)W[(k0 + j) * 128 + n];
  *(half8*)(Wf + (size_t)g * 8) = h;
}

// ---------------------------------------------------------------------------
// kv: K/V projections into MFMA-fragment-ordered global images.
// K: [tile(32r)][ct 0..1][kc 0..3][lane]*8   V: [tile(32r)][dt 0..7][lane]*8
// ---------------------------------------------------------------------------
__global__ __launch_bounds__(256) void kv_kernel(
    const float* __restrict__ x, const _Float16* __restrict__ Wf,
    _Float16* __restrict__ Kg, _Float16* __restrict__ Vg) {
  __shared__ __align__(16) _Float16 sc[64 * 136];
  const int tid = threadIdx.x;
  const int w = tid >> 6, lane = tid & 63;
  const int n16 = lane & 15, quad = lane >> 4;
  const int blk = blockIdx.x;  // 64 rows/block

  half8 xf[4];
  {
    const float* xr = x + (size_t)(blk * 64 + w * 16 + n16) * 128 + quad * 8;
#pragma unroll
    for (int kc = 0; kc < 4; ++kc) {
      float4 a = *(const float4*)(xr + kc * 32);
      float4 b = *(const float4*)(xr + kc * 32 + 4);
      half8 h;
      h[0] = (_Float16)a.x; h[1] = (_Float16)a.y;
      h[2] = (_Float16)a.z; h[3] = (_Float16)a.w;
      h[4] = (_Float16)b.x; h[5] = (_Float16)b.y;
      h[6] = (_Float16)b.z; h[7] = (_Float16)b.w;
      xf[kc] = h;
    }
  }

  for (int mat = 0; mat < 2; ++mat) {  // 0 -> Wk image(1), 1 -> Wv image(2)
    f32x4 acc[8];
#pragma unroll
    for (int ct = 0; ct < 8; ++ct) acc[ct] = f32x4{0.f, 0.f, 0.f, 0.f};
#pragma unroll
    for (int ct = 0; ct < 8; ++ct)
#pragma unroll
      for (int kc = 0; kc < 4; ++kc) {
        half8 wf = *(const half8*)(Wf +
            ((size_t)((mat + 1) * 32 + ct * 4 + kc) * 64 + lane) * 8);
        acc[ct] = mfma16(xf[kc], wf, acc[ct]);
      }
#pragma unroll
    for (int ct = 0; ct < 8; ++ct)
#pragma unroll
      for (int r = 0; r < 4; ++r)
        sc[(w * 16 + quad * 4 + r) * 136 + ct * 16 + n16] = (_Float16)acc[ct][r];
    __syncthreads();

    if (mat == 0) {  // K
#pragma unroll
      for (int i = 0; i < 4; ++i) {
        const int c = tid + 256 * i;
        const int ln = c & 63, kc = (c >> 6) & 3, ct = (c >> 8) & 1, tl = (c >> 9) & 1;
        half8 v = *(const half8*)&sc[(tl * 32 + ct * 16 + (ln & 15)) * 136 +
                                     kc * 32 + (ln >> 4) * 8];
        *(half8*)(Kg + ((((size_t)(blk * 2 + tl)) * 2 + ct) * 4 + kc) * 512 + ln * 8) = v;
      }
    } else {  // V transposed fragments
#pragma unroll
      for (int i = 0; i < 4; ++i) {
        const int c = tid + 256 * i;
        const int ln = c & 63, dt = (c >> 6) & 7, tl = (c >> 9) & 1;
        const int q2 = ln >> 4, nn = ln & 15;
        half8 v;
#pragma unroll
        for (int j = 0; j < 8; ++j)
          v[j] = sc[(tl * 32 + q2 * 8 + j) * 136 + dt * 16 + nn];
        *(half8*)(Vg + (((size_t)(blk * 2 + tl)) * 8 + dt) * 512 + ln * 8) = v;
      }
    }
    __syncthreads();
  }
}

// ---------------------------------------------------------------------------
// flash: 2 waves/block (32 q-rows), nsplit-way K-split, double-buffered
// global_load_lds staging, DPP softmax reductions, conn register prefetch.
// Writes normalized partial O (f16, A-frag order) + (m,l) per row per split.
// ---------------------------------------------------------------------------
__global__ __launch_bounds__(128) void flash_kernel(
    const float* __restrict__ x, const float* __restrict__ conn,
    const _Float16* __restrict__ Wf,
    const _Float16* __restrict__ Kg, const _Float16* __restrict__ Vg,
    _Float16* __restrict__ Og, float2* __restrict__ Ml,
    int nsplit, int nt) {
  __shared__ __align__(16) _Float16 kb[2][4096];
  __shared__ __align__(16) _Float16 vb[2][4096];
  __shared__ __align__(16) _Float16 pb[2][656];

  const int tid = threadIdx.x, w = tid >> 6, lane = tid & 63;
  const int n16 = lane & 15, quad = lane >> 4;
  const int bid = blockIdx.x;
  const int sk = bid & (nsplit - 1);
  const int rest = (nsplit == 2) ? (bid >> 1) : bid;
  const int batch = rest & 3;
  const int rg = rest >> 2;                      // 32-row group [0,128)
  const int rt_g = batch * 256 + rg * 2 + w;     // global rowtile
  const int t0 = sk * nt;

  // ---- Q = x @ Wq for this wave's 16 rows (once) ----
  half8 qf[4];
  {
    half8 xf[4];
    const float* xr = x + (size_t)(batch * 4096 + rg * 32 + w * 16 + n16) * 128 + quad * 8;
#pragma unroll
    for (int kc = 0; kc < 4; ++kc) {
      float4 a = *(const float4*)(xr + kc * 32);
      float4 b = *(const float4*)(xr + kc * 32 + 4);
      half8 h;
      h[0] = (_Float16)a.x; h[1] = (_Float16)a.y;
      h[2] = (_Float16)a.z; h[3] = (_Float16)a.w;
      h[4] = (_Float16)b.x; h[5] = (_Float16)b.y;
      h[6] = (_Float16)b.z; h[7] = (_Float16)b.w;
      xf[kc] = h;
    }
    _Float16* tw = &kb[w][0];
#pragma unroll
    for (int ct = 0; ct < 8; ++ct) {
      f32x4 aq = f32x4{0.f, 0.f, 0.f, 0.f};
#pragma unroll
      for (int kc = 0; kc < 4; ++kc) {
        half8 wf = *(const half8*)(Wf + ((size_t)(ct * 4 + kc) * 64 + lane) * 8);
        aq = mfma16(xf[kc], wf, aq);
      }
#pragma unroll
      for (int r = 0; r < 4; ++r)
        tw[(quad * 4 + r) * 136 + ct * 16 + n16] = (_Float16)aq[r];
    }
#pragma unroll
    for (int kc = 0; kc < 4; ++kc)
      qf[kc] = *(const half8*)(tw + n16 * 136 + kc * 32 + quad * 8);
  }
  __syncthreads();  // kb free for staging

  const _Float16* Kt = Kg + (size_t)batch * 524288;
  const _Float16* Vt = Vg + (size_t)batch * 524288;
  const float* cp = conn + (size_t)batch * 16777216 +
                    (size_t)(rg * 32 + w * 16 + quad * 4) * 4096 + n16 +
                    (size_t)t0 * 32;
  const int wbase = (tid & ~63) * 8;

  auto stage = [&](int t, int buf) {
    const _Float16* ks = Kt + (size_t)t * 4096 + tid * 8;
    const _Float16* vs = Vt + (size_t)t * 4096 + tid * 8;
#pragma unroll
    for (int c = 0; c < 4; ++c) {
      gload16(ks + c * 1024, &kb[buf][c * 1024 + wbase]);
      gload16(vs + c * 1024, &vb[buf][c * 1024 + wbase]);
    }
  };
  float cc[8], cn[8];
  auto ldconn = [&](int i, float* cr) {
    const float* c0 = cp + (size_t)i * 32;
#pragma unroll
    for (int ct = 0; ct < 2; ++ct)
#pragma unroll
      for (int r = 0; r < 4; ++r)
        cr[ct * 4 + r] = c0[(size_t)r * 4096 + ct * 16] * L2E;
  };

  f32x4 o[8];
#pragma unroll
  for (int dt = 0; dt < 8; ++dt) o[dt] = f32x4{0.f, 0.f, 0.f, 0.f};
  float m_i[4] = {-__builtin_inff(), -__builtin_inff(),
                  -__builtin_inff(), -__builtin_inff()};
  float l_i[4] = {0.f, 0.f, 0.f, 0.f};

  stage(t0, 0);
  ldconn(0, cc);
  __syncthreads();

#pragma unroll 1
  for (int i = 0; i < nt; ++i) {
    const int cur = i & 1, nxt = cur ^ 1;
    if (i + 1 < nt) {
      stage(t0 + i + 1, nxt);
      ldconn(i + 1, cn);
    }
    f32x4 s0 = f32x4{0.f, 0.f, 0.f, 0.f};
    f32x4 s1 = f32x4{0.f, 0.f, 0.f, 0.f};
#pragma unroll
    for (int kc = 0; kc < 4; ++kc) {
      half8 kf0 = *(const half8*)&kb[cur][(0 * 4 + kc) * 512 + lane * 8];
      half8 kf1 = *(const half8*)&kb[cur][(1 * 4 + kc) * 512 + lane * 8];
      s0 = mfma16(qf[kc], kf0, s0);
      s1 = mfma16(qf[kc], kf1, s1);
    }
    const float c1 = L2E * INV_SCALE;
    float pr[8];
#pragma unroll
    for (int r = 0; r < 4; ++r) pr[r] = fmaf(s0[r], c1, cc[r]);
#pragma unroll
    for (int r = 0; r < 4; ++r) pr[4 + r] = fmaf(s1[r], c1, cc[4 + r]);
    float mt[4];
#pragma unroll
    for (int r = 0; r < 4; ++r) mt[r] = red16_max(fmaxf(pr[r], pr[4 + r]));
    int upd = (mt[0] > m_i[0]) | (mt[1] > m_i[1]) |
              (mt[2] > m_i[2]) | (mt[3] > m_i[3]);
    if (__any(upd)) {
#pragma unroll
      for (int r = 0; r < 4; ++r) {
        const float mn = fmaxf(m_i[r], mt[r]);
        const float al = exp2_fast(m_i[r] - mn);
        m_i[r] = mn;
        l_i[r] *= al;
#pragma unroll
        for (int dt = 0; dt < 8; ++dt) o[dt][r] *= al;
      }
    }
#pragma unroll
    for (int c = 0; c < 8; ++c) pr[c] = exp2_fast(pr[c] - m_i[c & 3]);
#pragma unroll
    for (int r = 0; r < 4; ++r) l_i[r] += red16_sum(pr[r] + pr[4 + r]);
    // P: C-layout -> A-layout via per-wave LDS
    _Float16* pw = pb[w];
#pragma unroll
    for (int c = 0; c < 8; ++c)
      pw[(quad * 4 + (c & 3)) * 40 + (c >> 2) * 16 + n16] = (_Float16)pr[c];
    half8 pf = *(const half8*)(pw + n16 * 40 + quad * 8);
#pragma unroll
    for (int dt = 0; dt < 8; ++dt) {
      half8 vf = *(const half8*)&vb[cur][dt * 512 + lane * 8];
      o[dt] = mfma16(pf, vf, o[dt]);
    }
#pragma unroll
    for (int c = 0; c < 8; ++c) cc[c] = cn[c];
    __syncthreads();
  }

  // epilogue: normalize, transpose C->A per wave, store partial + (m,l)
  float il[4];
#pragma unroll
  for (int r = 0; r < 4; ++r) il[r] = 1.f / l_i[r];
  _Float16* tw = &kb[w][0];
#pragma unroll
  for (int dt = 0; dt < 8; ++dt)
#pragma unroll
    for (int r = 0; r < 4; ++r)
      tw[(quad * 4 + r) * 136 + dt * 16 + n16] = (_Float16)(o[dt][r] * il[r]);
  _Float16* ob = Og + ((size_t)(sk * 1024 + rt_g) * 4) * 512;
#pragma unroll
  for (int kc = 0; kc < 4; ++kc) {
    half8 of = *(const half8*)(tw + n16 * 136 + kc * 32 + quad * 8);
    *(half8*)(ob + kc * 512 + lane * 8) = of;
  }
  if (n16 == 0) {
#pragma unroll
    for (int r = 0; r < 4; ++r)
      Ml[sk * 16384 + rt_g * 16 + quad * 4 + r] = make_float2(m_i[r], l_i[r]);
  }
}

// ---------------------------------------------------------------------------
// mlp: merge K-split partials -> swish -> @W1+b1 -> swish -> @W2+b2 -> LN
// ---------------------------------------------------------------------------
__global__ __launch_bounds__(256) void mlp_kernel(
    const _Float16* __restrict__ Og, const float2* __restrict__ Ml,
    const _Float16* __restrict__ Wf,
    const float* __restrict__ b1, const float* __restrict__ b2,
    const float* __restrict__ gamma, const float* __restrict__ beta,
    float* __restrict__ out, int nsplit) {
  __shared__ __align__(16) _Float16 hb[4][2176];
  const int tid = threadIdx.x, w = tid >> 6, lane = tid & 63;
  const int n16 = lane & 15, quad = lane >> 4;
  const int rt_g = blockIdx.x * 4 + w;

  // merge partials (per-lane: all this lane's elements are row n16 of rt_g)
  float2 ml[2];
  float m = -__builtin_inff();
  for (int s = 0; s < nsplit; ++s) {
    ml[s] = Ml[s * 16384 + rt_g * 16 + n16];
    m = fmaxf(m, ml[s].x);
  }
  float wgt[2], wsum = 0.f;
  for (int s = 0; s < nsplit; ++s) {
    wgt[s] = ml[s].y * exp2_fast(ml[s].x - m);
    wsum += wgt[s];
  }
  const float inv = 1.f / wsum;

  half8 hf[4];
#pragma unroll
  for (int kc = 0; kc < 4; ++kc) {
    float hv[8] = {0, 0, 0, 0, 0, 0, 0, 0};
    for (int s = 0; s < nsplit; ++s) {
      half8 ofr = *(const half8*)(Og +
          ((size_t)(s * 1024 + rt_g) * 4 + kc) * 512 + lane * 8);
#pragma unroll
      for (int j = 0; j < 8; ++j) hv[j] += wgt[s] * (float)ofr[j];
    }
    half8 h;
#pragma unroll
    for (int j = 0; j < 8; ++j) h[j] = (_Float16)swish_f(hv[j] * inv);
    hf[kc] = h;
  }

  float b1v[8], b2v[8], gv[8], bv[8];
#pragma unroll
  for (int ct = 0; ct < 8; ++ct) {
    b1v[ct] = b1[ct * 16 + n16];
    b2v[ct] = b2[ct * 16 + n16];
    gv[ct] = gamma[ct * 16 + n16];
    bv[ct] = beta[ct * 16 + n16];
  }

  f32x4 acc[8];
#pragma unroll
  for (int ct = 0; ct < 8; ++ct) acc[ct] = f32x4{0.f, 0.f, 0.f, 0.f};
#pragma unroll
  for (int ct = 0; ct < 8; ++ct)
#pragma unroll
    for (int kc = 0; kc < 4; ++kc) {
      half8 wf = *(const half8*)(Wf +
          ((size_t)(3 * 32 + ct * 4 + kc) * 64 + lane) * 8);
      acc[ct] = mfma16(hf[kc], wf, acc[ct]);
    }
  _Float16* hw = hb[w];
#pragma unroll
  for (int ct = 0; ct < 8; ++ct)
#pragma unroll
    for (int r = 0; r < 4; ++r)
      hw[(quad * 4 + r) * 136 + ct * 16 + n16] =
          (_Float16)swish_f(acc[ct][r] + b1v[ct]);
  half8 h1f[4];
#pragma unroll
  for (int kc = 0; kc < 4; ++kc)
    h1f[kc] = *(const half8*)(hw + n16 * 136 + kc * 32 + quad * 8);

#pragma unroll
  for (int ct = 0; ct < 8; ++ct) acc[ct] = f32x4{0.f, 0.f, 0.f, 0.f};
#pragma unroll
  for (int ct = 0; ct < 8; ++ct)
#pragma unroll
    for (int kc = 0; kc < 4; ++kc) {
      half8 wf = *(const half8*)(Wf +
          ((size_t)(4 * 32 + ct * 4 + kc) * 64 + lane) * 8);
      acc[ct] = mfma16(h1f[kc], wf, acc[ct]);
    }
  float hx[8][4];
  float sm[4] = {0, 0, 0, 0}, ss[4] = {0, 0, 0, 0};
#pragma unroll
  for (int ct = 0; ct < 8; ++ct)
#pragma unroll
    for (int r = 0; r < 4; ++r) {
      const float v = acc[ct][r] + b2v[ct];
      hx[ct][r] = v;
      sm[r] += v;
      ss[r] += v * v;
    }
#pragma unroll
  for (int r = 0; r < 4; ++r) {
    sm[r] = red16_sum(sm[r]);
    ss[r] = red16_sum(ss[r]);
  }
#pragma unroll
  for (int r = 0; r < 4; ++r) {
    const float mu = sm[r] * (1.f / 128.f);
    const float var = ss[r] * (1.f / 128.f) - mu * mu;
    const float rstd = rsqrtf(var + 1e-5f);
    const size_t row = (size_t)rt_g * 16 + quad * 4 + r;
#pragma unroll
    for (int ct = 0; ct < 8; ++ct)
      out[row * 128 + ct * 16 + n16] = (hx[ct][r] - mu) * rstd * gv[ct] + bv[ct];
  }
}

extern "C" void kernel_launch(void* const* d_in, const int* in_sizes, int n_in,
                              void* d_out, int out_size, void* d_ws,
                              size_t ws_size, hipStream_t stream) {
  const float* x     = (const float*)d_in[0];
  const float* conn  = (const float*)d_in[1];
  const float* Wq    = (const float*)d_in[2];
  const float* Wk    = (const float*)d_in[3];
  const float* Wv    = (const float*)d_in[4];
  const float* W1    = (const float*)d_in[5];
  const float* b1    = (const float*)d_in[6];
  const float* W2    = (const float*)d_in[7];
  const float* b2    = (const float*)d_in[8];
  const float* gamma = (const float*)d_in[9];
  const float* beta  = (const float*)d_in[10];
  float* out = (float*)d_out;

  // ws layout (f16 elems): Wf[81920] | Kg[2M] | Vg[2M] | Og[2M*nsplit] | Ml
  const size_t need2 =
      ((size_t)81920 + 4 * 2097152) * 2 + 2 * 16384 * sizeof(float2);
  const int nsplit = (ws_size >= need2) ? 2 : 1;  // ws_size constant per session
  const int nt = 128 / nsplit;

  _Float16* Wf = (_Float16*)d_ws;
  _Float16* Kg = Wf + 81920;
  _Float16* Vg = Kg + 2097152;
  _Float16* Og = Vg + 2097152;
  float2* Ml = (float2*)(Og + (size_t)2097152 * nsplit);

  prep_kernel<<<40, 256, 0, stream>>>(Wq, Wk, Wv, W1, W2, Wf);
  kv_kernel<<<256, 256, 0, stream>>>(x, Wf, Kg, Vg);
  flash_kernel<<<512 * nsplit, 128, 0, stream>>>(x, conn, Wf, Kg, Vg, Og, Ml,
                                                 nsplit, nt);
  mlp_kernel<<<256, 256, 0, stream>>>(Og, Ml, Wf, b1, b2, gamma, beta, out,
                                      nsplit);
}

// Round 3
// 454.488 us; speedup vs baseline: 1.0733x; 1.0343x over previous
//
#include <hip/hip_runtime.h>

#define L2E 1.44269504088896340736f
#define INV_SCALE 0.08838834764831845f  // 1/sqrt(128)

typedef _Float16 half8 __attribute__((ext_vector_type(8)));
typedef _Float16 half4 __attribute__((ext_vector_type(4)));
typedef float f32x4 __attribute__((ext_vector_type(4)));

__device__ __forceinline__ float exp2_fast(float x) {
#if __has_builtin(__builtin_amdgcn_exp2f)
  return __builtin_amdgcn_exp2f(x);
#else
  return exp2f(x);
#endif
}

__device__ __forceinline__ f32x4 mfma16(half8 a, half8 b, f32x4 c) {
  return __builtin_amdgcn_mfma_f32_16x16x32_f16(a, b, c, 0, 0, 0);
}

__device__ __forceinline__ void gload16(const void* g, void* l) {
  __builtin_amdgcn_global_load_lds(
      (const __attribute__((address_space(1))) void*)g,
      (__attribute__((address_space(3))) void*)l, 16, 0, 0);
}

__device__ __forceinline__ float swish_f(float v) {
  return v / (1.f + exp2_fast(-L2E * v));
}

template <int CTRL>
__device__ __forceinline__ float dppmov(float x) {
  int xi = __builtin_bit_cast(int, x);
  int r = __builtin_amdgcn_update_dpp(xi, xi, CTRL, 0xf, 0xf, false);
  return __builtin_bit_cast(float, r);
}
__device__ __forceinline__ float red16_sum(float x) {
  x += dppmov<0xB1>(x);
  x += dppmov<0x4E>(x);
  x += dppmov<0x141>(x);
  x += dppmov<0x140>(x);
  return x;
}

// ---------------------------------------------------------------------------
// prep: f16 B-fragment images of the 5 weight matrices.
// frag f = ct*4+kc: Wf[((m*32+f)*64+lane)*8+j] = W[k][n],
//   n = ct*16 + (lane&15), k = kc*32 + (lane>>4)*8 + j
// ---------------------------------------------------------------------------
__global__ __launch_bounds__(256) void prep_kernel(
    const float* __restrict__ Wq, const float* __restrict__ Wk,
    const float* __restrict__ Wv, const float* __restrict__ W1,
    const float* __restrict__ W2, _Float16* __restrict__ Wf) {
  const int g = blockIdx.x * 256 + threadIdx.x;  // [0, 10240)
  const int mat = g >> 11, rem = g & 2047;
  const int f = rem >> 6, lane = rem & 63;
  const int n = (f >> 2) * 16 + (lane & 15);
  const int k0 = (f & 3) * 32 + (lane >> 4) * 8;
  const float* W = (mat == 0) ? Wq : (mat == 1) ? Wk : (mat == 2) ? Wv
                   : (mat == 3) ? W1 : W2;
  half8 h;
#pragma unroll
  for (int j = 0; j < 8; ++j) h[j] = (_Float16)W[(k0 + j) * 128 + n];
  *(half8*)(Wf + (size_t)g * 8) = h;
}

// ---------------------------------------------------------------------------
// kv: K/V projections into MFMA-fragment-ordered global images.
// K: [tile(32r)][ct 0..1][kc 0..3][lane]*8   V: [tile(32r)][dt 0..7][lane]*8
// ---------------------------------------------------------------------------
__global__ __launch_bounds__(256) void kv_kernel(
    const float* __restrict__ x, const _Float16* __restrict__ Wf,
    _Float16* __restrict__ Kg, _Float16* __restrict__ Vg) {
  __shared__ __align__(16) _Float16 sc[64 * 136];
  const int tid = threadIdx.x;
  const int w = tid >> 6, lane = tid & 63;
  const int n16 = lane & 15, quad = lane >> 4;
  const int blk = blockIdx.x;  // 64 rows/block

  half8 xf[4];
  {
    const float* xr = x + (size_t)(blk * 64 + w * 16 + n16) * 128 + quad * 8;
#pragma unroll
    for (int kc = 0; kc < 4; ++kc) {
      float4 a = *(const float4*)(xr + kc * 32);
      float4 b = *(const float4*)(xr + kc * 32 + 4);
      half8 h;
      h[0] = (_Float16)a.x; h[1] = (_Float16)a.y;
      h[2] = (_Float16)a.z; h[3] = (_Float16)a.w;
      h[4] = (_Float16)b.x; h[5] = (_Float16)b.y;
      h[6] = (_Float16)b.z; h[7] = (_Float16)b.w;
      xf[kc] = h;
    }
  }

  for (int mat = 0; mat < 2; ++mat) {  // 0 -> Wk image(1), 1 -> Wv image(2)
    f32x4 acc[8];
#pragma unroll
    for (int ct = 0; ct < 8; ++ct) acc[ct] = f32x4{0.f, 0.f, 0.f, 0.f};
#pragma unroll
    for (int ct = 0; ct < 8; ++ct)
#pragma unroll
      for (int kc = 0; kc < 4; ++kc) {
        half8 wf = *(const half8*)(Wf +
            ((size_t)((mat + 1) * 32 + ct * 4 + kc) * 64 + lane) * 8);
        acc[ct] = mfma16(xf[kc], wf, acc[ct]);
      }
#pragma unroll
    for (int ct = 0; ct < 8; ++ct)
#pragma unroll
      for (int r = 0; r < 4; ++r)
        sc[(w * 16 + quad * 4 + r) * 136 + ct * 16 + n16] = (_Float16)acc[ct][r];
    __syncthreads();

    if (mat == 0) {  // K
#pragma unroll
      for (int i = 0; i < 4; ++i) {
        const int c = tid + 256 * i;
        const int ln = c & 63, kc = (c >> 6) & 3, ct = (c >> 8) & 1, tl = (c >> 9) & 1;
        half8 v = *(const half8*)&sc[(tl * 32 + ct * 16 + (ln & 15)) * 136 +
                                     kc * 32 + (ln >> 4) * 8];
        *(half8*)(Kg + ((((size_t)(blk * 2 + tl)) * 2 + ct) * 4 + kc) * 512 + ln * 8) = v;
      }
    } else {  // V transposed fragments
#pragma unroll
      for (int i = 0; i < 4; ++i) {
        const int c = tid + 256 * i;
        const int ln = c & 63, dt = (c >> 6) & 7, tl = (c >> 9) & 1;
        const int q2 = ln >> 4, nn = ln & 15;
        half8 v;
#pragma unroll
        for (int j = 0; j < 8; ++j)
          v[j] = sc[(tl * 32 + q2 * 8 + j) * 136 + dt * 16 + nn];
        *(half8*)(Vg + (((size_t)(blk * 2 + tl)) * 8 + dt) * 512 + ln * 8) = v;
      }
    }
    __syncthreads();
  }
}

// ---------------------------------------------------------------------------
// flash: S^T = K.Q^T layout. Each lane holds 8 scores of ONE q-row (q=n16);
// conn arrives via two coalesced float4 loads directly into the right lanes;
// softmax reductions are 7 in-register ops + 2 shfl_xor. Online m/l is one
// scalar per lane; o-rescale factors cross layouts via a 16-float LDS
// broadcast. 2 waves/block, double-buffered K/V staging via global_load_lds.
// ---------------------------------------------------------------------------
__global__ __launch_bounds__(128) void flash_kernel(
    const float* __restrict__ x, const float* __restrict__ conn,
    const _Float16* __restrict__ Wf,
    const _Float16* __restrict__ Kg, const _Float16* __restrict__ Vg,
    _Float16* __restrict__ Og, float2* __restrict__ Ml,
    int nsplit, int nt) {
  __shared__ __align__(16) _Float16 kb[2][4096];
  __shared__ __align__(16) _Float16 vb[2][4096];
  __shared__ __align__(16) _Float16 pb[2][656];
  __shared__ __align__(16) float alb[2][16];

  const int tid = threadIdx.x, w = tid >> 6, lane = tid & 63;
  const int n16 = lane & 15, quad = lane >> 4;
  const int bid = blockIdx.x;
  // decode so bid mod 8 fixes (batch, sk): each XCD serves one K/V half-image
  int batch, sk, rg;
  if (nsplit == 2) {
    batch = bid & 3; sk = (bid >> 2) & 1; rg = bid >> 3;
  } else {
    batch = bid & 3; sk = 0; rg = bid >> 2;
  }
  const int rt_g = batch * 256 + rg * 2 + w;
  const int t0 = sk * nt;

  // ---- Q = x @ Wq for this wave's 16 rows (once); kb[w] as scratch ----
  half8 qf[4];
  {
    half8 xf[4];
    const float* xr = x + (size_t)(batch * 4096 + rg * 32 + w * 16 + n16) * 128 + quad * 8;
#pragma unroll
    for (int kc = 0; kc < 4; ++kc) {
      float4 a = *(const float4*)(xr + kc * 32);
      float4 b = *(const float4*)(xr + kc * 32 + 4);
      half8 h;
      h[0] = (_Float16)a.x; h[1] = (_Float16)a.y;
      h[2] = (_Float16)a.z; h[3] = (_Float16)a.w;
      h[4] = (_Float16)b.x; h[5] = (_Float16)b.y;
      h[6] = (_Float16)b.z; h[7] = (_Float16)b.w;
      xf[kc] = h;
    }
    _Float16* tw = &kb[w][0];
#pragma unroll
    for (int ct = 0; ct < 8; ++ct) {
      f32x4 aq = f32x4{0.f, 0.f, 0.f, 0.f};
#pragma unroll
      for (int kc = 0; kc < 4; ++kc) {
        half8 wf = *(const half8*)(Wf + ((size_t)(ct * 4 + kc) * 64 + lane) * 8);
        aq = mfma16(xf[kc], wf, aq);
      }
#pragma unroll
      for (int r = 0; r < 4; ++r)
        tw[(quad * 4 + r) * 136 + ct * 16 + n16] = (_Float16)aq[r];
    }
#pragma unroll
    for (int kc = 0; kc < 4; ++kc)
      qf[kc] = *(const half8*)(tw + n16 * 136 + kc * 32 + quad * 8);
  }
  __syncthreads();  // scratch reads drained; kb free for staging

  const _Float16* kp = Kg + (size_t)batch * 524288 + (size_t)t0 * 4096 + tid * 8;
  const _Float16* vp = Vg + (size_t)batch * 524288 + (size_t)t0 * 4096 + tid * 8;
  const float* cp = conn + (size_t)batch * 16777216 +
                    (size_t)(rg * 32 + w * 16 + n16) * 4096 +
                    (size_t)t0 * 32 + quad * 4;
  const int wbase = (tid & ~63) * 8;

  auto stage = [&](int t, int buf) {
    const _Float16* ks = kp + (size_t)t * 4096;
    const _Float16* vs = vp + (size_t)t * 4096;
#pragma unroll
    for (int c = 0; c < 4; ++c) {
      gload16(ks + c * 1024, &kb[buf][c * 1024 + wbase]);
      gload16(vs + c * 1024, &vb[buf][c * 1024 + wbase]);
    }
  };
  auto ldconn = [&](int i, float4* cr) {
    const float* c0 = cp + (size_t)i * 32;
    cr[0] = *(const float4*)c0;
    cr[1] = *(const float4*)(c0 + 16);
  };

  f32x4 o[8];
#pragma unroll
  for (int dt = 0; dt < 8; ++dt) o[dt] = f32x4{0.f, 0.f, 0.f, 0.f};
  float m_i = -__builtin_inff();
  float l_i = 0.f;

  float4 ca[2], cb[2];
  stage(0, 0);
  ldconn(0, ca);
  __syncthreads();

  auto compute = [&](int buf, const float4* cc) {
    f32x4 s0 = f32x4{0.f, 0.f, 0.f, 0.f};
    f32x4 s1 = f32x4{0.f, 0.f, 0.f, 0.f};
    const _Float16* kc_ = kb[buf];
#pragma unroll
    for (int kc = 0; kc < 4; ++kc) {
      half8 kf0 = *(const half8*)&kc_[kc * 512 + lane * 8];
      half8 kf1 = *(const half8*)&kc_[(4 + kc) * 512 + lane * 8];
      s0 = mfma16(kf0, qf[kc], s0);  // S^T: A=K, B=Q
      s1 = mfma16(kf1, qf[kc], s1);
    }
    float pr[8];
#pragma unroll
    for (int r = 0; r < 4; ++r) {
      pr[r] = fmaf(s0[r], INV_SCALE, cc[0][r]);
      pr[4 + r] = fmaf(s1[r], INV_SCALE, cc[1][r]);
    }
    float mx = pr[0];
#pragma unroll
    for (int c = 1; c < 8; ++c) mx = fmaxf(mx, pr[c]);
    mx = fmaxf(mx, __shfl_xor(mx, 16, 64));
    mx = fmaxf(mx, __shfl_xor(mx, 32, 64));
    if (__any(mx > m_i)) {
      const float mn = fmaxf(m_i, mx);
      const float al = exp2_fast((m_i - mn) * L2E);
      m_i = mn;
      l_i *= al;
      if (quad == 0) alb[w][n16] = al;
      const float4 av = *(const float4*)&alb[w][quad * 4];
#pragma unroll
      for (int dt = 0; dt < 8; ++dt)
#pragma unroll
        for (int r = 0; r < 4; ++r) o[dt][r] *= av[r];
    }
    const float nm = -m_i * L2E;
#pragma unroll
    for (int c = 0; c < 8; ++c) pr[c] = exp2_fast(fmaf(pr[c], L2E, nm));
    float sm = pr[0];
#pragma unroll
    for (int c = 1; c < 8; ++c) sm += pr[c];
    sm += __shfl_xor(sm, 16, 64);
    sm += __shfl_xor(sm, 32, 64);
    l_i += sm;
    // P^T -> pw[q][k] (stride 40), two packed b64 writes; b128 A-frag read
    _Float16* pw = pb[w];
    half4 p0, p1;
#pragma unroll
    for (int r = 0; r < 4; ++r) {
      p0[r] = (_Float16)pr[r];
      p1[r] = (_Float16)pr[4 + r];
    }
    *(half4*)(pw + n16 * 40 + quad * 4) = p0;
    *(half4*)(pw + n16 * 40 + 16 + quad * 4) = p1;
    half8 pf = *(const half8*)(pw + n16 * 40 + quad * 8);
    const _Float16* vc = vb[buf];
#pragma unroll
    for (int dt = 0; dt < 8; ++dt) {
      half8 vf = *(const half8*)&vc[dt * 512 + lane * 8];
      o[dt] = mfma16(pf, vf, o[dt]);
    }
  };

#pragma unroll 1
  for (int i = 0; i < nt; i += 2) {
    stage(i + 1, 1);
    ldconn(i + 1, cb);
    compute(0, ca);
    __syncthreads();
    if (i + 2 < nt) {
      stage(i + 2, 0);
      ldconn(i + 2, ca);
    }
    compute(1, cb);
    __syncthreads();
  }

  // epilogue: transpose l via LDS broadcast, normalize, store A-frag order
  if (quad == 0) alb[w][n16] = l_i;
  const float4 lv = *(const float4*)&alb[w][quad * 4];
  float il[4];
#pragma unroll
  for (int r = 0; r < 4; ++r) il[r] = 1.f / lv[r];
  _Float16* tw = &kb[w][0];
#pragma unroll
  for (int dt = 0; dt < 8; ++dt)
#pragma unroll
    for (int r = 0; r < 4; ++r)
      tw[(quad * 4 + r) * 136 + dt * 16 + n16] = (_Float16)(o[dt][r] * il[r]);
  _Float16* ob = Og + ((size_t)(sk * 1024 + rt_g) * 4) * 512;
#pragma unroll
  for (int kc = 0; kc < 4; ++kc) {
    half8 of = *(const half8*)(tw + n16 * 136 + kc * 32 + quad * 8);
    *(half8*)(ob + kc * 512 + lane * 8) = of;
  }
  if (quad == 0)
    Ml[sk * 16384 + rt_g * 16 + n16] = make_float2(m_i, l_i);
}

// ---------------------------------------------------------------------------
// mlp: merge K-split partials -> swish -> @W1+b1 -> swish -> @W2+b2 -> LN
// ---------------------------------------------------------------------------
__global__ __launch_bounds__(256) void mlp_kernel(
    const _Float16* __restrict__ Og, const float2* __restrict__ Ml,
    const _Float16* __restrict__ Wf,
    const float* __restrict__ b1, const float* __restrict__ b2,
    const float* __restrict__ gamma, const float* __restrict__ beta,
    float* __restrict__ out, int nsplit) {
  __shared__ __align__(16) _Float16 hb[4][2176];
  const int tid = threadIdx.x, w = tid >> 6, lane = tid & 63;
  const int n16 = lane & 15, quad = lane >> 4;
  const int rt_g = blockIdx.x * 4 + w;

  // merge partials (per-lane: all this lane's elements are row n16 of rt_g)
  float2 ml[2];
  float m = -__builtin_inff();
  for (int s = 0; s < nsplit; ++s) {
    ml[s] = Ml[s * 16384 + rt_g * 16 + n16];
    m = fmaxf(m, ml[s].x);
  }
  float wgt[2], wsum = 0.f;
  for (int s = 0; s < nsplit; ++s) {
    wgt[s] = ml[s].y * exp2_fast((ml[s].x - m) * L2E);  // m raw-score domain
    wsum += wgt[s];
  }
  const float inv = 1.f / wsum;

  half8 hf[4];
#pragma unroll
  for (int kc = 0; kc < 4; ++kc) {
    float hv[8] = {0, 0, 0, 0, 0, 0, 0, 0};
    for (int s = 0; s < nsplit; ++s) {
      half8 ofr = *(const half8*)(Og +
          ((size_t)(s * 1024 + rt_g) * 4 + kc) * 512 + lane * 8);
#pragma unroll
      for (int j = 0; j < 8; ++j) hv[j] += wgt[s] * (float)ofr[j];
    }
    half8 h;
#pragma unroll
    for (int j = 0; j < 8; ++j) h[j] = (_Float16)swish_f(hv[j] * inv);
    hf[kc] = h;
  }

  float b1v[8], b2v[8], gv[8], bv[8];
#pragma unroll
  for (int ct = 0; ct < 8; ++ct) {
    b1v[ct] = b1[ct * 16 + n16];
    b2v[ct] = b2[ct * 16 + n16];
    gv[ct] = gamma[ct * 16 + n16];
    bv[ct] = beta[ct * 16 + n16];
  }

  f32x4 acc[8];
#pragma unroll
  for (int ct = 0; ct < 8; ++ct) acc[ct] = f32x4{0.f, 0.f, 0.f, 0.f};
#pragma unroll
  for (int ct = 0; ct < 8; ++ct)
#pragma unroll
    for (int kc = 0; kc < 4; ++kc) {
      half8 wf = *(const half8*)(Wf +
          ((size_t)(3 * 32 + ct * 4 + kc) * 64 + lane) * 8);
      acc[ct] = mfma16(hf[kc], wf, acc[ct]);
    }
  _Float16* hw = hb[w];
#pragma unroll
  for (int ct = 0; ct < 8; ++ct)
#pragma unroll
    for (int r = 0; r < 4; ++r)
      hw[(quad * 4 + r) * 136 + ct * 16 + n16] =
          (_Float16)swish_f(acc[ct][r] + b1v[ct]);
  half8 h1f[4];
#pragma unroll
  for (int kc = 0; kc < 4; ++kc)
    h1f[kc] = *(const half8*)(hw + n16 * 136 + kc * 32 + quad * 8);

#pragma unroll
  for (int ct = 0; ct < 8; ++ct) acc[ct] = f32x4{0.f, 0.f, 0.f, 0.f};
#pragma unroll
  for (int ct = 0; ct < 8; ++ct)
#pragma unroll
    for (int kc = 0; kc < 4; ++kc) {
      half8 wf = *(const half8*)(Wf +
          ((size_t)(4 * 32 + ct * 4 + kc) * 64 + lane) * 8);
      acc[ct] = mfma16(h1f[kc], wf, acc[ct]);
    }
  float hx[8][4];
  float sm[4] = {0, 0, 0, 0}, ss[4] = {0, 0, 0, 0};
#pragma unroll
  for (int ct = 0; ct < 8; ++ct)
#pragma unroll
    for (int r = 0; r < 4; ++r) {
      const float v = acc[ct][r] + b2v[ct];
      hx[ct][r] = v;
      sm[r] += v;
      ss[r] += v * v;
    }
#pragma unroll
  for (int r = 0; r < 4; ++r) {
    sm[r] = red16_sum(sm[r]);
    ss[r] = red16_sum(ss[r]);
  }
#pragma unroll
  for (int r = 0; r < 4; ++r) {
    const float mu = sm[r] * (1.f / 128.f);
    const float var = ss[r] * (1.f / 128.f) - mu * mu;
    const float rstd = rsqrtf(var + 1e-5f);
    const size_t row = (size_t)rt_g * 16 + quad * 4 + r;
#pragma unroll
    for (int ct = 0; ct < 8; ++ct)
      out[row * 128 + ct * 16 + n16] = (hx[ct][r] - mu) * rstd * gv[ct] + bv[ct];
  }
}

extern "C" void kernel_launch(void* const* d_in, const int* in_sizes, int n_in,
                              void* d_out, int out_size, void* d_ws,
                              size_t ws_size, hipStream_t stream) {
  const float* x     = (const float*)d_in[0];
  const float* conn  = (const float*)d_in[1];
  const float* Wq    = (const float*)d_in[2];
  const float* Wk    = (const float*)d_in[3];
  const float* Wv    = (const float*)d_in[4];
  const float* W1    = (const float*)d_in[5];
  const float* b1    = (const float*)d_in[6];
  const float* W2    = (const float*)d_in[7];
  const float* b2    = (const float*)d_in[8];
  const float* gamma = (const float*)d_in[9];
  const float* beta  = (const float*)d_in[10];
  float* out = (float*)d_out;

  // ws layout (f16 elems): Wf[81920] | Kg[2M] | Vg[2M] | Og[2M*nsplit] | Ml
  const size_t need2 =
      ((size_t)81920 + 4 * 2097152) * 2 + 2 * 16384 * sizeof(float2);
  const int nsplit = (ws_size >= need2) ? 2 : 1;  // ws_size constant per session
  const int nt = 128 / nsplit;

  _Float16* Wf = (_Float16*)d_ws;
  _Float16* Kg = Wf + 81920;
  _Float16* Vg = Kg + 2097152;
  _Float16* Og = Vg + 2097152;
  float2* Ml = (float2*)(Og + (size_t)2097152 * nsplit);

  prep_kernel<<<40, 256, 0, stream>>>(Wq, Wk, Wv, W1, W2, Wf);
  kv_kernel<<<256, 256, 0, stream>>>(x, Wf, Kg, Vg);
  flash_kernel<<<512 * nsplit, 128, 0, stream>>>(x, conn, Wf, Kg, Vg, Og, Ml,
                                                 nsplit, nt);
  mlp_kernel<<<256, 256, 0, stream>>>(Og, Ml, Wf, b1, b2, gamma, beta, out,
                                      nsplit);
}